// Round 1
// baseline (486.866 us; speedup 1.0000x reference)
//
#include <hip/hip_runtime.h>

// Tensor-ring FFN, fp32 baseline.
// Decomposition (R=16, ring-state r*r=256):
//  L1: z1 = x[6144,512] @ GdT[512,256]          (GEMM)
//      s1[b,256] = sum_{l,r6} z1 * Pseq1        (fold)
//      u1[6144,256] = s1 x c1_out_seq           (expand)
//      h = relu(u1 @ F1[256,2048] + b1)         (GEMM)
//  L2: z2 = h @ GffT[2048,256]                  (GEMM)
//      s2 = fold(z2, c2_in_seq)
//      u2 = expand(s2, Qseq2)
//      y = u2 @ OdT[256,512] + b2               (GEMM)

// ---------------- chain fold: 5x(16,2,16) + (16,3,16) -> P[16,96,16] --------
__global__ void build_chain_kernel(
    const float* __restrict__ a5, const float* __restrict__ a3,
    const float* __restrict__ b5, const float* __restrict__ b3,
    float* __restrict__ Pout, float* __restrict__ Qout)
{
    __shared__ float bufA[8192];
    __shared__ float bufB[4096];
    const float* cores5 = (blockIdx.x == 0) ? a5 : b5;
    const float* core3  = (blockIdx.x == 0) ? a3 : b3;
    float* out = (blockIdx.x == 0) ? Pout : Qout;
    const int tid = threadIdx.x;

    for (int i = tid; i < 512; i += 256) bufA[i] = cores5[i];
    __syncthreads();

    float* prev = bufA; float* next = bufB;
    int m = 2;
    for (int g = 1; g < 5; ++g) {
        const float* G = cores5 + g * 512;           // [16,2,16]
        const int mnew = m * 2;
        const int total = 256 * mnew;
        for (int idx = tid; idx < total; idx += 256) {
            const int rn = idx & 15;
            const int mm = (idx >> 4) % mnew;
            const int r0 = idx / (mnew * 16);
            const int mp = mm >> 1, i = mm & 1;
            float acc = 0.f;
            #pragma unroll
            for (int r = 0; r < 16; ++r)
                acc += prev[(r0 * m + mp) * 16 + r] * G[r * 32 + i * 16 + rn];
            next[idx] = acc;
        }
        __syncthreads();
        float* t = prev; prev = next; next = t;
        m = mnew;
    }
    // final: (16,3,16) -> out[16,96,16] in global
    {
        const int mnew = m * 3;                      // 96
        const int total = 256 * mnew;                // 24576
        for (int idx = tid; idx < total; idx += 256) {
            const int rn = idx & 15;
            const int mm = (idx >> 4) % mnew;
            const int r0 = idx / (mnew * 16);
            const int mp = mm / 3, i = mm % 3;
            float acc = 0.f;
            #pragma unroll
            for (int r = 0; r < 16; ++r)
                acc += prev[(r0 * m + mp) * 16 + r] * core3[r * 48 + i * 16 + rn];
            out[idx] = acc;
        }
    }
}

// ---- permutes of (16,N,16) cores into GEMM layouts ----
// out[n*256 + i*16 + j] = in[(i*N + n)*16 + j]   (B-matrix [N x 256])
__global__ void perm_mid_kernel(const float* __restrict__ in, float* __restrict__ out, int N) {
    const int idx = blockIdx.x * 256 + threadIdx.x;
    const int n = idx >> 8, r = idx & 255, i = r >> 4, j = r & 15;
    out[idx] = in[(i * N + n) * 16 + j];
}
// out[(i*16+j)*N + n] = in[(i*N + n)*16 + j]     (B-matrix [256 x N])
__global__ void perm_out_kernel(const float* __restrict__ in, float* __restrict__ out, int N) {
    const int idx = blockIdx.x * 256 + threadIdx.x;
    const int k = idx / N, n = idx - k * N, i = k >> 4, j = k & 15;
    out[idx] = in[(i * N + n) * 16 + j];
}

// ---- ring fold: s[b, r0*16+rE] = sum_{l<96,r<16} z[(b*96+l)*256 + r*16+rE] * P[(r0*96+l)*16+r]
__global__ void sfold_kernel(const float* __restrict__ z, const float* __restrict__ P,
                             float* __restrict__ s) {
    const int b = blockIdx.x, tid = threadIdx.x;
    const int r0 = tid >> 4, rE = tid & 15;
    const float* zb = z + b * 96 * 256;
    float acc = 0.f;
    for (int l = 0; l < 96; ++l) {
        const float* zl = zb + l * 256 + rE;
        const float* Pl = P + (r0 * 96 + l) * 16;
        #pragma unroll
        for (int r = 0; r < 16; ++r) acc += zl[r * 16] * Pl[r];
    }
    s[b * 256 + tid] = acc;
}

// ---- expand: u[(b*96+o1)*256 + dd*16+a] = sum_c s[b*256 + a*16+c] * O[(c*96+o1)*16+dd]
__global__ void uexpand_kernel(const float* __restrict__ s, const float* __restrict__ O,
                               float* __restrict__ u) {
    __shared__ float s_sh[256], o_sh[256];
    const int o1 = blockIdx.x, b = blockIdx.y, tid = threadIdx.x;
    s_sh[tid] = s[b * 256 + tid];
    o_sh[tid] = O[((tid >> 4) * 96 + o1) * 16 + (tid & 15)];
    __syncthreads();
    const int dd = tid >> 4, a = tid & 15;
    float acc = 0.f;
    #pragma unroll
    for (int c = 0; c < 16; ++c) acc += s_sh[a * 16 + c] * o_sh[c * 16 + dd];
    u[(b * 96 + o1) * 256 + tid] = acc;
}

// ---- fp32 GEMM: C[M,N] = A[M,K] @ B[K,N] (+bias[(m%96)*N+n]) (+relu) ----
// 64x64 tile, BK=16, 256 threads, 4x4 micro-tile.
template<int BIAS, int RELU>
__global__ __launch_bounds__(256) void gemm64_kernel(
    const float* __restrict__ A, const float* __restrict__ B,
    const float* __restrict__ bias, float* __restrict__ C,
    int M, int N, int K)
{
    __shared__ float As[16][64];
    __shared__ float Bs[16][64];
    const int n0 = blockIdx.x * 64, m0 = blockIdx.y * 64;
    const int tid = threadIdx.x;
    const int arow = tid >> 2, aseg = tid & 3;
    const int bk = tid >> 4, bn4 = (tid & 15) * 4;
    const int tm = (tid >> 4) * 4, tn = (tid & 15) * 4;
    float acc[4][4] = {};

    for (int kt = 0; kt < K; kt += 16) {
        const float4 av = *(const float4*)(A + (size_t)(m0 + arow) * K + kt + aseg * 4);
        const float4 bv = *(const float4*)(B + (size_t)(kt + bk) * N + n0 + bn4);
        As[aseg * 4 + 0][arow] = av.x;
        As[aseg * 4 + 1][arow] = av.y;
        As[aseg * 4 + 2][arow] = av.z;
        As[aseg * 4 + 3][arow] = av.w;
        *(float4*)(&Bs[bk][bn4]) = bv;
        __syncthreads();
        #pragma unroll
        for (int k = 0; k < 16; ++k) {
            const float4 a4 = *(const float4*)(&As[k][tm]);
            const float4 b4 = *(const float4*)(&Bs[k][tn]);
            const float am[4] = {a4.x, a4.y, a4.z, a4.w};
            const float bn_[4] = {b4.x, b4.y, b4.z, b4.w};
            #pragma unroll
            for (int i = 0; i < 4; ++i)
                #pragma unroll
                for (int j = 0; j < 4; ++j)
                    acc[i][j] += am[i] * bn_[j];
        }
        __syncthreads();
    }

    #pragma unroll
    for (int i = 0; i < 4; ++i) {
        const int m = m0 + tm + i;
        float4 v = make_float4(acc[i][0], acc[i][1], acc[i][2], acc[i][3]);
        if (BIAS) {
            const float4 bb = *(const float4*)(bias + (size_t)(m % 96) * N + n0 + tn);
            v.x += bb.x; v.y += bb.y; v.z += bb.z; v.w += bb.w;
        }
        if (RELU) {
            v.x = fmaxf(v.x, 0.f); v.y = fmaxf(v.y, 0.f);
            v.z = fmaxf(v.z, 0.f); v.w = fmaxf(v.w, 0.f);
        }
        *(float4*)(C + (size_t)m * N + n0 + tn) = v;
    }
}

extern "C" void kernel_launch(void* const* d_in, const int* in_sizes, int n_in,
                              void* d_out, int out_size, void* d_ws, size_t ws_size,
                              hipStream_t stream) {
    const float* x        = (const float*)d_in[0];   // [64,96,512]
    const float* c1_in2   = (const float*)d_in[1];   // [5,16,2,16]
    const float* c1_in3   = (const float*)d_in[2];   // [16,3,16]
    const float* c1_ind   = (const float*)d_in[3];   // [16,512,16]
    const float* c1_oseq  = (const float*)d_in[4];   // [16,96,16]
    const float* c1_off   = (const float*)d_in[5];   // [16,2048,16]
    const float* b1       = (const float*)d_in[6];   // [96*2048]
    const float* c2_iseq  = (const float*)d_in[7];   // [16,96,16]
    const float* c2_iff   = (const float*)d_in[8];   // [16,2048,16]
    const float* c2_out2  = (const float*)d_in[9];   // [5,16,2,16]
    const float* c2_out3  = (const float*)d_in[10];  // [16,3,16]
    const float* c2_outd  = (const float*)d_in[11];  // [16,512,16]
    const float* b2       = (const float*)d_in[12];  // [96*512]
    float* out = (float*)d_out;

    float* ws = (float*)d_ws;
    float* Pseq1 = ws;                    // 24576
    float* Qseq2 = Pseq1 + 24576;         // 24576
    float* GdT   = Qseq2 + 24576;         // 512*256
    float* F1    = GdT + 512 * 256;       // 256*2048
    float* GffT  = F1 + 256 * 2048;       // 2048*256
    float* OdT   = GffT + 2048 * 256;     // 256*512
    float* z1    = OdT + 256 * 512;       // 6144*256
    float* s1    = z1 + 6144 * 256;       // 64*256
    float* u1    = s1 + 64 * 256;         // 6144*256
    float* h     = u1 + 6144 * 256;       // 6144*2048
    float* z2    = h + (size_t)6144 * 2048; // 6144*256
    float* s2    = z2 + 6144 * 256;       // 64*256
    float* u2    = s2 + 64 * 256;         // 6144*256

    // 1) fold seq-mode cores into P[16,96,16] (both layers)
    build_chain_kernel<<<2, 256, 0, stream>>>(c1_in2, c1_in3, c2_out2, c2_out3, Pseq1, Qseq2);
    // 2) core transposes into GEMM layouts
    perm_mid_kernel<<<512, 256, 0, stream>>>(c1_ind, GdT, 512);    // [512,256]
    perm_mid_kernel<<<2048, 256, 0, stream>>>(c2_iff, GffT, 2048); // [2048,256]
    perm_out_kernel<<<2048, 256, 0, stream>>>(c1_off, F1, 2048);   // [256,2048]
    perm_out_kernel<<<512, 256, 0, stream>>>(c2_outd, OdT, 512);   // [256,512]

    // 3) layer 1
    gemm64_kernel<0, 0><<<dim3(256 / 64, 6144 / 64), 256, 0, stream>>>(x, GdT, nullptr, z1, 6144, 256, 512);
    sfold_kernel<<<64, 256, 0, stream>>>(z1, Pseq1, s1);
    uexpand_kernel<<<dim3(96, 64), 256, 0, stream>>>(s1, c1_oseq, u1);
    gemm64_kernel<1, 1><<<dim3(2048 / 64, 6144 / 64), 256, 0, stream>>>(u1, F1, b1, h, 6144, 2048, 256);

    // 4) layer 2
    gemm64_kernel<0, 0><<<dim3(256 / 64, 6144 / 64), 256, 0, stream>>>(h, GffT, nullptr, z2, 6144, 256, 2048);
    sfold_kernel<<<64, 256, 0, stream>>>(z2, c2_iseq, s2);
    uexpand_kernel<<<dim3(96, 64), 256, 0, stream>>>(s2, Qseq2, u2);
    gemm64_kernel<1, 0><<<dim3(512 / 64, 6144 / 64), 256, 0, stream>>>(u2, OdT, b2, out, 6144, 512, 256);
}

// Round 2
// 270.484 us; speedup vs baseline: 1.8000x; 1.8000x over previous
//
#include <hip/hip_runtime.h>

// Tensor-ring FFN on MI355X — f16-split MFMA (AhBh + AhBl + AlBh, fp32 acc).
//  L1: z1 = x @ GdT          [6144,512]x[512,256]   MFMA, SK=2
//      s1 = ringfold(z1,P1); u1 = expand(s1,H1)     (split-half out)
//      h  = relu(u1 @ F1 + b1) [6144,256]x[256,2048] MFMA (split-half out)
//  L2: z2 = h @ GffT         [6144,2048]x[2048,256] MFMA, SK=2
//      s2 = ringfold(z2,c2_iseq); u2 = expand(s2,Q)
//      y  = u2 @ OdT + b2    [6144,256]x[256,512]   MFMA -> d_out fp32

typedef _Float16 f16;
typedef f16 f16x8 __attribute__((ext_vector_type(8)));
typedef f16 f16x4 __attribute__((ext_vector_type(4)));
typedef float f32x4 __attribute__((ext_vector_type(4)));

// ---------------- chain fold: 5x(16,2,16) + (16,3,16) -> P[16,96,16] --------
__global__ void build_chain_kernel(
    const float* __restrict__ a5, const float* __restrict__ a3,
    const float* __restrict__ b5, const float* __restrict__ b3,
    float* __restrict__ Pout, float* __restrict__ Qout)
{
    __shared__ float bufA[8192];
    __shared__ float bufB[4096];
    const float* cores5 = (blockIdx.x == 0) ? a5 : b5;
    const float* core3  = (blockIdx.x == 0) ? a3 : b3;
    float* out = (blockIdx.x == 0) ? Pout : Qout;
    const int tid = threadIdx.x;

    for (int i = tid; i < 512; i += 256) bufA[i] = cores5[i];
    __syncthreads();

    float* prev = bufA; float* next = bufB;
    int m = 2;
    for (int g = 1; g < 5; ++g) {
        const float* G = cores5 + g * 512;           // [16,2,16]
        const int mnew = m * 2;
        const int total = 256 * mnew;
        for (int idx = tid; idx < total; idx += 256) {
            const int rn = idx & 15;
            const int mm = (idx >> 4) % mnew;
            const int r0 = idx / (mnew * 16);
            const int mp = mm >> 1, i = mm & 1;
            float acc = 0.f;
            #pragma unroll
            for (int r = 0; r < 16; ++r)
                acc += prev[(r0 * m + mp) * 16 + r] * G[r * 32 + i * 16 + rn];
            next[idx] = acc;
        }
        __syncthreads();
        float* t = prev; prev = next; next = t;
        m = mnew;
    }
    {
        const int mnew = m * 3;                      // 96
        const int total = 256 * mnew;
        for (int idx = tid; idx < total; idx += 256) {
            const int rn = idx & 15;
            const int mm = (idx >> 4) % mnew;
            const int r0 = idx / (mnew * 16);
            const int mp = mm / 3, i = mm % 3;
            float acc = 0.f;
            #pragma unroll
            for (int r = 0; r < 16; ++r)
                acc += prev[(r0 * m + mp) * 16 + r] * core3[r * 48 + i * 16 + rn];
            out[idx] = acc;
        }
    }
}

// ---- B^T builders (split to f16 h/l) ----
// Type M (ring = n, middle = k): BT[n*K + k] = core[((n>>4)*K + k)*16 + (n&15)]
// LDS-tiled: grid (N/16=16, K/256); 256 thr.
__global__ void permM_kernel(const float* __restrict__ in, f16* __restrict__ bh,
                             f16* __restrict__ bl, int K) {
    __shared__ float t[4096];
    const int q = blockIdx.x, k0 = blockIdx.y * 256;
    const float* src = in + ((size_t)q * K + k0) * 16;
    for (int i = threadIdx.x; i < 1024; i += 256)
        ((float4*)t)[i] = ((const float4*)src)[i];       // t[k_local*16 + j]
    __syncthreads();
    const int j = threadIdx.x >> 4, kc = (threadIdx.x & 15) * 16;
    f16* dh = bh + (size_t)(q * 16 + j) * K + k0 + kc;
    f16* dl = bl + (size_t)(q * 16 + j) * K + k0 + kc;
    f16 vh[16], vl[16];
    #pragma unroll
    for (int i = 0; i < 16; ++i) {
        const float v = t[(kc + i) * 16 + j];
        const f16 h = (f16)v;
        vh[i] = h; vl[i] = (f16)(v - (float)h);
    }
    *(f16x8*)(dh) = *(f16x8*)&vh[0]; *(f16x8*)(dh + 8) = *(f16x8*)&vh[8];
    *(f16x8*)(dl) = *(f16x8*)&vl[0]; *(f16x8*)(dl + 8) = *(f16x8*)&vl[8];
}
// Type O (ring = k, middle = n): BT[n*256 + k] = core[((k>>4)*N + n)*16 + (k&15)]
__global__ void permO_kernel(const float* __restrict__ in, f16* __restrict__ bh,
                             f16* __restrict__ bl, int N) {
    const int idx = blockIdx.x * 256 + threadIdx.x;
    const int n = idx >> 8, k = idx & 255;
    const float v = in[((k >> 4) * N + n) * 16 + (k & 15)];
    const f16 h = (f16)v;
    bh[idx] = h; bl[idx] = (f16)(v - (float)h);
}

// ---- x -> split halves ----
__global__ void xsplit_kernel(const float* __restrict__ x, f16* __restrict__ xh,
                              f16* __restrict__ xl) {
    const int idx = blockIdx.x * 256 + threadIdx.x;
    const float4 v = ((const float4*)x)[idx];
    f16x4 hh, ll;
    hh[0] = (f16)v.x; hh[1] = (f16)v.y; hh[2] = (f16)v.z; hh[3] = (f16)v.w;
    ll[0] = (f16)(v.x - (float)hh[0]); ll[1] = (f16)(v.y - (float)hh[1]);
    ll[2] = (f16)(v.z - (float)hh[2]); ll[3] = (f16)(v.w - (float)hh[3]);
    ((f16x4*)xh)[idx] = hh; ((f16x4*)xl)[idx] = ll;
}

// ---- ring fold with split-K partials: grid (64 b, 6 lc) ----
// spart[(lc*64+b)*256 + r0*16+rE] = sum_{sk, l in chunk, r6} z[sk][b*96+l][r6*16+rE]*P[r0,l,r6]
__global__ void sfold_kernel(const float* __restrict__ z, const float* __restrict__ P,
                             float* __restrict__ spart, int SK) {
    const int b = blockIdx.x, lc = blockIdx.y, tid = threadIdx.x;
    const int r0 = tid >> 4, rE = tid & 15;
    float acc = 0.f;
    for (int sk = 0; sk < SK; ++sk) {
        const float* zb = z + ((size_t)sk * 6144 + b * 96) * 256;
        for (int l = lc * 16; l < lc * 16 + 16; ++l) {
            const float* zl = zb + l * 256 + rE;
            const float* Pl = P + (r0 * 96 + l) * 16;
            #pragma unroll
            for (int r = 0; r < 16; ++r) acc += zl[r * 16] * Pl[r];
        }
    }
    spart[((size_t)lc * 64 + b) * 256 + tid] = acc;
}

// ---- expand: u[(b*96+o1)*256 + tid] = sum_c s[b, a*16+c... ] -> split halves
__global__ void uexpand_kernel(const float* __restrict__ spart, const float* __restrict__ O,
                               f16* __restrict__ uh, f16* __restrict__ ul) {
    __shared__ float s_sh[256], o_sh[256];
    const int o1 = blockIdx.x, b = blockIdx.y, tid = threadIdx.x;
    float sv = 0.f;
    #pragma unroll
    for (int lc = 0; lc < 6; ++lc) sv += spart[((size_t)lc * 64 + b) * 256 + tid];
    s_sh[tid] = sv;
    o_sh[tid] = O[((tid >> 4) * 96 + o1) * 16 + (tid & 15)];
    __syncthreads();
    const int dd = tid >> 4, a = tid & 15;
    float acc = 0.f;
    #pragma unroll
    for (int c = 0; c < 16; ++c) acc += s_sh[a * 16 + c] * o_sh[c * 16 + dd];
    const f16 h = (f16)acc;
    const size_t o = ((size_t)b * 96 + o1) * 256 + tid;
    uh[o] = h; ul[o] = (f16)(acc - (float)h);
}

// ---- f16-split MFMA GEMM: C = A @ BT^T ; BM=64, BN=128, BK=32, 4 waves ----
// A[M][K] as halves (Ah,Al); BT[N][K] as halves (BTh,BTl).
// EPI 0: Cf[bz][M][N] = v (split-K partial)
// EPI 1: v+=bias; relu; split-> Ch/Cl[M][N]
// EPI 2: v+=bias; Cf[M][N] = v
template<int EPI>
__global__ __launch_bounds__(256) void trgemm_kernel(
    const f16* __restrict__ Ah, const f16* __restrict__ Al,
    const f16* __restrict__ BTh, const f16* __restrict__ BTl,
    const float* __restrict__ bias,
    float* __restrict__ Cf, f16* __restrict__ Ch, f16* __restrict__ Cl,
    int M, int N, int K, int kchunk)
{
    __shared__ f16 As[2][4 * 512];   // [hl][mf*512 + lane*8 + i]  (frag order)
    __shared__ f16 Bs[2][8 * 512];   // [hl][nfg*512 + lane*8 + i]
    const int n0 = blockIdx.x * 128, m0 = blockIdx.y * 64;
    const int kbase = blockIdx.z * kchunk;
    const int tid = threadIdx.x;
    const int w = tid >> 6, lane = tid & 63;

    const int ar = tid >> 2, aq = tid & 3;     // A staging: row, 8-half quad
    const int bn = tid >> 1, bsg = tid & 1;    // B staging: n-local, 16-half seg
    const size_t a_off = (size_t)(m0 + ar) * K + kbase + aq * 8;
    const size_t b_off = (size_t)(n0 + bn) * K + kbase + bsg * 16;
    const int a_w = (ar >> 4) * 512 + aq * 128 + (ar & 15) * 8;
    const int b_w = (bn >> 4) * 512 + (bsg * 2) * 128 + (bn & 15) * 8;

    f32x4 acc[4][2];
    #pragma unroll
    for (int i = 0; i < 4; ++i) { acc[i][0] = (f32x4)0.f; acc[i][1] = (f32x4)0.f; }

    const int nkt = kchunk >> 5;
    for (int kt = 0; kt < nkt; ++kt) {
        const size_t ao = a_off + (size_t)kt * 32;
        const size_t bo = b_off + (size_t)kt * 32;
        const f16x8 avh = *(const f16x8*)(Ah + ao);
        const f16x8 avl = *(const f16x8*)(Al + ao);
        const f16x8 bvh0 = *(const f16x8*)(BTh + bo);
        const f16x8 bvh1 = *(const f16x8*)(BTh + bo + 8);
        const f16x8 bvl0 = *(const f16x8*)(BTl + bo);
        const f16x8 bvl1 = *(const f16x8*)(BTl + bo + 8);
        __syncthreads();                       // LDS free from prev iter reads
        *(f16x8*)&As[0][a_w] = avh;
        *(f16x8*)&As[1][a_w] = avl;
        *(f16x8*)&Bs[0][b_w] = bvh0;
        *(f16x8*)&Bs[0][b_w + 128] = bvh1;
        *(f16x8*)&Bs[1][b_w] = bvl0;
        *(f16x8*)&Bs[1][b_w + 128] = bvl1;
        __syncthreads();
        f16x8 afh[4], afl[4], bfh[2], bfl[2];
        #pragma unroll
        for (int mf = 0; mf < 4; ++mf) {
            afh[mf] = *(const f16x8*)&As[0][mf * 512 + lane * 8];
            afl[mf] = *(const f16x8*)&As[1][mf * 512 + lane * 8];
        }
        #pragma unroll
        for (int nf = 0; nf < 2; ++nf) {
            bfh[nf] = *(const f16x8*)&Bs[0][(w * 2 + nf) * 512 + lane * 8];
            bfl[nf] = *(const f16x8*)&Bs[1][(w * 2 + nf) * 512 + lane * 8];
        }
        #pragma unroll
        for (int mf = 0; mf < 4; ++mf)
            #pragma unroll
            for (int nf = 0; nf < 2; ++nf) {
                acc[mf][nf] = __builtin_amdgcn_mfma_f32_16x16x32_f16(afh[mf], bfh[nf], acc[mf][nf], 0, 0, 0);
                acc[mf][nf] = __builtin_amdgcn_mfma_f32_16x16x32_f16(afh[mf], bfl[nf], acc[mf][nf], 0, 0, 0);
                acc[mf][nf] = __builtin_amdgcn_mfma_f32_16x16x32_f16(afl[mf], bfh[nf], acc[mf][nf], 0, 0, 0);
            }
    }

    const int g = lane >> 4, c = lane & 15;    // D: row=(lane>>4)*4+r, col=lane&15
    #pragma unroll
    for (int mf = 0; mf < 4; ++mf)
        #pragma unroll
        for (int nf = 0; nf < 2; ++nf)
            #pragma unroll
            for (int r = 0; r < 4; ++r) {
                const int row = m0 + mf * 16 + g * 4 + r;
                const int col = n0 + w * 32 + nf * 16 + c;
                float v = acc[mf][nf][r];
                if constexpr (EPI == 0) {
                    Cf[((size_t)blockIdx.z * M + row) * N + col] = v;
                } else {
                    v += bias[(row % 96) * N + col];
                    if constexpr (EPI == 1) {
                        v = fmaxf(v, 0.f);
                        const f16 h = (f16)v;
                        Ch[(size_t)row * N + col] = h;
                        Cl[(size_t)row * N + col] = (f16)(v - (float)h);
                    } else {
                        Cf[(size_t)row * N + col] = v;
                    }
                }
            }
}

extern "C" void kernel_launch(void* const* d_in, const int* in_sizes, int n_in,
                              void* d_out, int out_size, void* d_ws, size_t ws_size,
                              hipStream_t stream) {
    const float* x        = (const float*)d_in[0];   // [64,96,512]
    const float* c1_in2   = (const float*)d_in[1];   // [5,16,2,16]
    const float* c1_in3   = (const float*)d_in[2];   // [16,3,16]
    const float* c1_ind   = (const float*)d_in[3];   // [16,512,16]
    const float* c1_oseq  = (const float*)d_in[4];   // [16,96,16]
    const float* c1_off   = (const float*)d_in[5];   // [16,2048,16]
    const float* b1       = (const float*)d_in[6];   // [96*2048]
    const float* c2_iseq  = (const float*)d_in[7];   // [16,96,16]
    const float* c2_iff   = (const float*)d_in[8];   // [16,2048,16]
    const float* c2_out2  = (const float*)d_in[9];   // [5,16,2,16]
    const float* c2_out3  = (const float*)d_in[10];  // [16,3,16]
    const float* c2_outd  = (const float*)d_in[11];  // [16,512,16]
    const float* b2       = (const float*)d_in[12];  // [96*512]
    float* out = (float*)d_out;

    float* wsf = (float*)d_ws;
    float* Pseq1 = wsf;                     // 24576 f
    float* Qseq2 = Pseq1 + 24576;           // 24576 f
    float* spart = Qseq2 + 24576;           // 98304 f (shared L1/L2)
    float* zp    = spart + 98304;           // 2*6144*256 f (z1 partials, then z2)
    f16* fb   = (f16*)(zp + 2 * 6144 * 256);
    f16* BT1h = fb;                         // 131072
    f16* BT1l = BT1h + 131072;
    f16* BT2h = BT1l + 131072;              // 524288
    f16* BT2l = BT2h + 524288;
    f16* BT3h = BT2l + 524288;              // 524288
    f16* BT3l = BT3h + 524288;
    f16* BT4h = BT3l + 524288;              // 131072
    f16* BT4l = BT4h + 131072;
    f16* uh   = BT4l + 131072;              // 1572864 (shared u1/u2)
    f16* ul   = uh + 1572864;
    f16* hh   = ul + 1572864;               // 12582912
    f16* hl   = hh + 12582912;
    f16* xh   = hh;                         // alias: x-split dies before h is written
    f16* xl   = hh + 3145728;

    // consts
    build_chain_kernel<<<2, 256, 0, stream>>>(c1_in2, c1_in3, c2_out2, c2_out3, Pseq1, Qseq2);
    permM_kernel<<<dim3(16, 2), 256, 0, stream>>>(c1_ind, BT1h, BT1l, 512);
    permO_kernel<<<2048, 256, 0, stream>>>(c1_off, BT2h, BT2l, 2048);
    permM_kernel<<<dim3(16, 8), 256, 0, stream>>>(c2_iff, BT3h, BT3l, 2048);
    permO_kernel<<<512, 256, 0, stream>>>(c2_outd, BT4h, BT4l, 512);
    xsplit_kernel<<<3072, 256, 0, stream>>>(x, xh, xl);

    // layer 1
    trgemm_kernel<0><<<dim3(2, 96, 2), 256, 0, stream>>>(xh, xl, BT1h, BT1l, nullptr,
                                                         zp, nullptr, nullptr, 6144, 256, 512, 256);
    sfold_kernel<<<dim3(64, 6), 256, 0, stream>>>(zp, Pseq1, spart, 2);
    uexpand_kernel<<<dim3(96, 64), 256, 0, stream>>>(spart, c1_oseq, uh, ul);
    trgemm_kernel<1><<<dim3(16, 96, 1), 256, 0, stream>>>(uh, ul, BT2h, BT2l, b1,
                                                          nullptr, hh, hl, 6144, 2048, 256, 256);
    // layer 2
    trgemm_kernel<0><<<dim3(2, 96, 2), 256, 0, stream>>>(hh, hl, BT3h, BT3l, nullptr,
                                                         zp, nullptr, nullptr, 6144, 256, 2048, 1024);
    sfold_kernel<<<dim3(64, 6), 256, 0, stream>>>(zp, c2_iseq, spart, 2);
    uexpand_kernel<<<dim3(96, 64), 256, 0, stream>>>(spart, Qseq2, uh, ul);
    trgemm_kernel<2><<<dim3(4, 96, 1), 256, 0, stream>>>(uh, ul, BT4h, BT4l, b2,
                                                         out, nullptr, nullptr, 6144, 512, 256, 256);
}